// Round 2
// baseline (377.191 us; speedup 1.0000x reference)
//
#include <hip/hip_runtime.h>

#define B_ 32
#define T_ 128
#define R_ 49
#define D_ 512
#define HE_ 256
#define HC_ 256

#define NBLK 256       // persistent grid: 1 block/CU, guaranteed co-resident
#define NG_GEMM1 354   // 256 wh-tiles + 98 rh-tiles
#define NG_K1 512      // 8 tokens per virtual block

typedef float f32x4 __attribute__((ext_vector_type(4)));
typedef short s16x8 __attribute__((ext_vector_type(8)));
typedef short s16x4 __attribute__((ext_vector_type(4)));

__device__ __forceinline__ unsigned short bf16rne(float f) {
  unsigned u = __float_as_uint(f);
  u += 0x7FFF + ((u >> 16) & 1);
  return (unsigned short)(u >> 16);
}
__device__ __forceinline__ float rcp_fast(float x) {
  return __builtin_amdgcn_rcpf(x);
}
__device__ __forceinline__ float tanh_fast(float x) {
  float e = __expf(2.0f * x);
  return fmaf(-2.0f, rcp_fast(e + 1.0f), 1.0f);
}
__device__ __forceinline__ float sigmoid_fast(float x) {
  return rcp_fast(1.0f + __expf(-x));
}
__device__ __forceinline__ float wave_sum(float v) {
#pragma unroll
  for (int off = 32; off; off >>= 1) v += __shfl_down(v, off);
  return v;  // total valid in lane 0
}

// Device-scope grid barrier. Safe because grid == NBLK == 256 == #CUs, so
// every block is resident (any kernel with <=64KB LDS fits >=1 block/CU).
// bar is zeroed by pack_w (stream-ordered before mega); monotonic arrivals,
// barrier k waits for k*NBLK.
__device__ __forceinline__ void grid_barrier(unsigned* bar, unsigned target) {
  __threadfence();  // flush my writes to device scope (wb L2)
  __syncthreads();
  if (threadIdx.x == 0) {
    __hip_atomic_fetch_add(bar, 1u, __ATOMIC_ACQ_REL, __HIP_MEMORY_SCOPE_AGENT);
    while (__hip_atomic_load(bar, __ATOMIC_ACQUIRE,
                             __HIP_MEMORY_SCOPE_AGENT) < target) {
      __builtin_amdgcn_s_sleep(1);
    }
  }
  __syncthreads();
  __threadfence();  // invalidate stale L1/L2 before reading others' writes
}

// ---------------------------------------------------------------------------
// pack_w: repack nw1 (mat0) and pw1 (mat1) [512][256] fp32 -> bf16 B-fragment
// order [mat][kt16][ct16][lane64][j8]. Also zeroes counter, grid-barrier
// counter, and the nst/nsr marginals (graph-replay-safe re-init each call).
// ---------------------------------------------------------------------------
__global__ __launch_bounds__(256) void pack_w(
    const float* __restrict__ nw1, const float* __restrict__ pw1,
    unsigned short* __restrict__ wp, unsigned* __restrict__ counter,
    unsigned* __restrict__ bar, float* __restrict__ nst,
    float* __restrict__ nsr) {
  int gid = blockIdx.x * 256 + threadIdx.x;  // 0..32767
  if (gid == 0) { counter[0] = 0u; bar[0] = 0u; }
  if (gid < B_ * T_) nst[gid] = 0.f;
  if (gid < B_ * R_) nsr[gid] = 0.f;
  int mat = gid >> 14;
  int rem = gid & 16383;
  int lane = rem & 63;
  int tile = rem >> 6;
  int kt = tile >> 4, ct = tile & 15;
  const float* W = mat ? pw1 : nw1;
  int k0 = kt * 32 + (lane >> 4) * 8;
  int c = ct * 16 + (lane & 15);
  s16x8 pk;
#pragma unroll
  for (int j = 0; j < 8; ++j)
    pk[j] = (short)bf16rne(W[(size_t)(k0 + j) * HE_ + c]);
  *(s16x8*)(wp + (size_t)gid * 8) = pk;
}

// ---------------------------------------------------------------------------
// mega: persistent fused pipeline.
//   stage A: {wh,rh} MFMA-GEMM + k1 attn/softmax/pos/compaction
//   stage B: hp=pos@pw1 + pscore  |  neg-expert over compacted list -> nst/nsr
//   stage C: per-(b,dchunk) aggregates nagg/pagg
//   stage D: per-b tail (choose/path_prob/final/classifier)
// Grid barriers between stages replace 3 kernel-launch boundaries.
// ---------------------------------------------------------------------------
__global__ __launch_bounds__(512) void mega(
    const float* __restrict__ word, const float* __restrict__ region,
    const unsigned short* __restrict__ wpack, const float* __restrict__ nb1,
    const int* __restrict__ amask, const float* __restrict__ pb1,
    const float* __restrict__ pw2, const float* __restrict__ pb2,
    const float* __restrict__ nw2, const float* __restrict__ nb2,
    const float* __restrict__ fcw, const float* __restrict__ fcb,
    const float* __restrict__ cw1, const float* __restrict__ cb1,
    const float* __restrict__ cw2, const float* __restrict__ cb2,
    float* __restrict__ wh, float* __restrict__ rh, float* __restrict__ pos,
    float* __restrict__ negcnt, unsigned* __restrict__ list,
    unsigned* __restrict__ counter, float* __restrict__ pscore,
    float* __restrict__ nst, float* __restrict__ nsr,
    float* __restrict__ nagg, float* __restrict__ pagg,
    unsigned* __restrict__ bar, float* __restrict__ out) {
  __shared__ alignas(16) unsigned short As[16 * 512];  // also hp_s fp32[16][256]
  __shared__ float attn_s[8][52];
  __shared__ alignas(16) float wp_T[49][8];
  __shared__ int wcnt_s[8];
  __shared__ int woff_s[8];
  __shared__ unsigned base_s;
  __shared__ float sred[16][4];
  __shared__ float nst_s[T_], psc_s[T_], nsr_s[R_];
  __shared__ float redn[8][64], redp[8][64];
  __shared__ float na_s[D_], pa_s[D_], fin[D_];
  __shared__ float red[16];
  __shared__ float pp_s[2];

  int tid = threadIdx.x, wave = tid >> 6, lane = tid & 63;
  int bid = blockIdx.x;

  // ======================= stage A: m1 GEMM + k1 ==========================
  for (int vb = bid; vb < NG_GEMM1 + NG_K1; vb += NBLK) {
    __syncthreads();  // LDS reuse guard between virtual blocks
    if (vb < NG_GEMM1) {
      const float* A;
      float* outp;
      int row0;
      bool useb;
      if (vb < 256) {
        A = word; outp = wh; row0 = vb * 16; useb = true;
      } else {
        A = region; outp = rh; row0 = (vb - 256) * 16; useb = false;
      }
      const float4* A4 = (const float4*)(A + (size_t)row0 * D_);
#pragma unroll
      for (int it = 0; it < 4; ++it) {
        int f = it * 512 + tid;
        int row = f >> 7, kq = f & 127;
        float4 v = A4[f];
        int bo = (row * 1024 + kq * 8) ^ ((row & 7) << 4);
        s16x4 pk;
        pk[0] = (short)bf16rne(v.x);
        pk[1] = (short)bf16rne(v.y);
        pk[2] = (short)bf16rne(v.z);
        pk[3] = (short)bf16rne(v.w);
        *(s16x4*)((char*)As + bo) = pk;
      }
      __syncthreads();
      int rl = lane & 15, kg = lane >> 4;
      f32x4 acc0 = {0.f, 0.f, 0.f, 0.f}, acc1 = {0.f, 0.f, 0.f, 0.f};
      const s16x8* Wp8 = (const s16x8*)wpack;  // mat 0 = nw1
      int ct0 = wave, ct1 = wave + 8;
#pragma unroll
      for (int kt = 0; kt < 16; ++kt) {
        int bo = (rl * 1024 + kt * 64 + kg * 16) ^ ((rl & 7) << 4);
        s16x8 af = *(const s16x8*)((char*)As + bo);
        s16x8 b0 = Wp8[(size_t)(kt * 16 + ct0) * 64 + lane];
        s16x8 b1 = Wp8[(size_t)(kt * 16 + ct1) * 64 + lane];
        acc0 = __builtin_amdgcn_mfma_f32_16x16x32_bf16(af, b0, acc0, 0, 0, 0);
        acc1 = __builtin_amdgcn_mfma_f32_16x16x32_bf16(af, b1, acc1, 0, 0, 0);
      }
      // C/D layout (m89-verified): col = lane&15, row = (lane>>4)*4 + reg
      float bb0 = useb ? nb1[ct0 * 16 + rl] : 0.f;
      float bb1 = useb ? nb1[ct1 * 16 + rl] : 0.f;
      int r0 = row0 + kg * 4;
#pragma unroll
      for (int q = 0; q < 4; ++q) {
        outp[(size_t)(r0 + q) * HE_ + ct0 * 16 + rl] = acc0[q] + bb0;
        outp[(size_t)(r0 + q) * HE_ + ct1 * 16 + rl] = acc1[q] + bb1;
      }
    } else {
      // ---- k1: 8 tokens, fp32 (hard threshold at 0.1 needs fp32 attn)
      int bid2 = vb - NG_GEMM1;
      int b = bid2 >> 4;
      int t0 = (bid2 & 15) * 8;
      int bt0 = b * T_ + t0;
      const float* reg = region + (size_t)b * R_ * D_;

      const float4* word4 = (const float4*)word;
      float4 wv[8][2];
#pragma unroll
      for (int t = 0; t < 8; ++t)
#pragma unroll
        for (int j = 0; j < 2; ++j)
          wv[t][j] = word4[(size_t)(bt0 + t) * 128 + lane * 2 + j];

      for (int r = wave; r < R_; r += 8) {
        const float4* rrow4 = (const float4*)(reg + (size_t)r * D_);
        float4 rv0 = rrow4[lane * 2 + 0];
        float4 rv1 = rrow4[lane * 2 + 1];
#pragma unroll
        for (int t = 0; t < 8; ++t) {
          float4 w0 = wv[t][0], w1 = wv[t][1];
          float acc = 0.f;
          acc = fmaf(w0.x, rv0.x, acc);
          acc = fmaf(w0.y, rv0.y, acc);
          acc = fmaf(w0.z, rv0.z, acc);
          acc = fmaf(w0.w, rv0.w, acc);
          acc = fmaf(w1.x, rv1.x, acc);
          acc = fmaf(w1.y, rv1.y, acc);
          acc = fmaf(w1.z, rv1.z, acc);
          acc = fmaf(w1.w, rv1.w, acc);
          acc = wave_sum(acc);
          if (lane == 0) attn_s[t][r] = acc;
        }
      }
      __syncthreads();

      bool want;
      unsigned long long bm;
      {
        int t = wave;  // 8 waves, one token each
        int am = amask[bt0 + t];
        float a = (lane < R_) ? attn_s[t][lane] : 0.f;
        float neg = (lane < R_ && (a - 0.1f) > 0.f) ? 1.f : 0.f;
        float masked =
            (lane < R_) ? ((neg > 0.f) ? a * 4.0f : -4e9f) : -3.0e38f;
        float cnt = wave_sum(neg);
        float m = masked;
#pragma unroll
        for (int off = 32; off; off >>= 1) m = fmaxf(m, __shfl_down(m, off));
        m = __shfl(m, 0);
        float e = (lane < R_) ? __expf(masked - m) : 0.f;
        float s = wave_sum(e);
        s = __shfl(s, 0);
        if (lane < R_) wp_T[lane][t] = e / s;
        if (lane == 0) negcnt[bt0 + t] = cnt;
        want = (lane < R_) && (neg == 0.f) && (am != 0);
        bm = __ballot(want);
        if (lane == 0) wcnt_s[wave] = __popcll(bm);
      }
      __syncthreads();
      if (tid == 0) {
        int tot = 0;
#pragma unroll
        for (int w = 0; w < 8; ++w) { woff_s[w] = tot; tot += wcnt_s[w]; }
        base_s = atomicAdd(counter, (unsigned)tot);  // ONE atomic per vblock
      }
      __syncthreads();
      if (want) {
        int prefix = __popcll(bm & ((1ull << lane) - 1ull));
        list[base_s + (unsigned)woff_s[wave] + (unsigned)prefix] =
            (unsigned)((bt0 + wave) * R_ + lane);
      }

      // pos: thread owns d = tid (512 = D), 8 token accumulators
      int d = tid;
      float accs[8] = {0.f, 0.f, 0.f, 0.f, 0.f, 0.f, 0.f, 0.f};
#pragma unroll 7
      for (int r = 0; r < R_; ++r) {
        float g = reg[(size_t)r * D_ + d];
        float4 w0 = *(const float4*)&wp_T[r][0];
        float4 w1 = *(const float4*)&wp_T[r][4];
        accs[0] = fmaf(w0.x, g, accs[0]);
        accs[1] = fmaf(w0.y, g, accs[1]);
        accs[2] = fmaf(w0.z, g, accs[2]);
        accs[3] = fmaf(w0.w, g, accs[3]);
        accs[4] = fmaf(w1.x, g, accs[4]);
        accs[5] = fmaf(w1.y, g, accs[5]);
        accs[6] = fmaf(w1.z, g, accs[6]);
        accs[7] = fmaf(w1.w, g, accs[7]);
      }
#pragma unroll
      for (int t = 0; t < 8; ++t) {
        size_t base = (size_t)(bt0 + t) * D_ + d;
        pos[base] = word[base] + accs[t];
      }
    }
  }
  grid_barrier(bar, NBLK);

  // ================= stage B: m2 GEMM (pscore) + neg-expert ===============
  {
    int row0 = bid * 16;  // exactly 256 tiles over 256 blocks
    const float4* A4 = (const float4*)(pos + (size_t)row0 * D_);
#pragma unroll
    for (int it = 0; it < 4; ++it) {
      int f = it * 512 + tid;
      int row = f >> 7, kq = f & 127;
      float4 v = A4[f];
      int bo = (row * 1024 + kq * 8) ^ ((row & 7) << 4);
      s16x4 pk;
      pk[0] = (short)bf16rne(v.x);
      pk[1] = (short)bf16rne(v.y);
      pk[2] = (short)bf16rne(v.z);
      pk[3] = (short)bf16rne(v.w);
      *(s16x4*)((char*)As + bo) = pk;
    }
    __syncthreads();
    int rl = lane & 15, kg = lane >> 4;
    f32x4 acc0 = {0.f, 0.f, 0.f, 0.f}, acc1 = {0.f, 0.f, 0.f, 0.f};
    const s16x8* Wp8 = (const s16x8*)wpack + 16384;  // mat 1 = pw1
    int ct0 = wave, ct1 = wave + 8;
#pragma unroll
    for (int kt = 0; kt < 16; ++kt) {
      int bo = (rl * 1024 + kt * 64 + kg * 16) ^ ((rl & 7) << 4);
      s16x8 af = *(const s16x8*)((char*)As + bo);
      s16x8 b0 = Wp8[(size_t)(kt * 16 + ct0) * 64 + lane];
      s16x8 b1 = Wp8[(size_t)(kt * 16 + ct1) * 64 + lane];
      acc0 = __builtin_amdgcn_mfma_f32_16x16x32_bf16(af, b0, acc0, 0, 0, 0);
      acc1 = __builtin_amdgcn_mfma_f32_16x16x32_bf16(af, b1, acc1, 0, 0, 0);
    }
    __syncthreads();  // all A-tile reads done; reuse LDS for hp
    float* hp_s = (float*)As;  // [16][256] fp32 = 16 KB
#pragma unroll
    for (int q = 0; q < 4; ++q) {
      hp_s[(kg * 4 + q) * 256 + ct0 * 16 + rl] = acc0[q];
      hp_s[(kg * 4 + q) * 256 + ct1 * 16 + rl] = acc1[q];
    }
    __syncthreads();
    int c = tid & 255, jh = tid >> 8;  // wave w covers c-chunk (w&3), jh=w>>2
    float pb1c = pb1[c], pw2c = pw2[c];
#pragma unroll
    for (int jj = 0; jj < 8; ++jj) {
      int j = jh * 8 + jj;
      float v = tanh_fast(hp_s[j * 256 + c] + pb1c) * pw2c;
      v = wave_sum(v);
      if (lane == 0) sred[j][wave & 3] = v;
    }
    __syncthreads();
    if (tid < 16) {
      float s = sred[tid][0] + sred[tid][1] + sred[tid][2] + sred[tid][3] +
                pb2[0];
      s = sigmoid_fast(s);
      int row = row0 + tid;
      if (negcnt[row] == 0.f) s = 0.f;
      s *= (float)amask[row];
      pscore[row] = fmaxf(s, 0.f);
    }
  }
  {
    // neg-expert over compacted list: 16-lane group per pair, grid-stride
    int grp = tid >> 4, gl = tid & 15;
    unsigned count = counter[0];  // finalized at stage-A barrier
    const float4* n4 = (const float4*)(nw2 + gl * 16);
    float4 wn0 = n4[0], wn1 = n4[1], wn2 = n4[2], wn3 = n4[3];
    float bias = nb2[0];
    for (unsigned i = (unsigned)bid * 32u + (unsigned)grp; i < count;
         i += (unsigned)NBLK * 32u) {
      unsigned pair = list[i];
      int bt = (int)(pair / R_);
      int r = (int)(pair - (unsigned)bt * R_);
      int b = bt >> 7;
      const float4* whp = (const float4*)(wh + (size_t)bt * HE_ + gl * 16);
      const float4* rhp =
          (const float4*)(rh + ((size_t)b * R_ + r) * HE_ + gl * 16);
      float acc = 0.f;
      float4 hw, hr;
      hw = whp[0]; hr = rhp[0];
      acc = fmaf(tanh_fast(hw.x + hr.x), wn0.x, acc);
      acc = fmaf(tanh_fast(hw.y + hr.y), wn0.y, acc);
      acc = fmaf(tanh_fast(hw.z + hr.z), wn0.z, acc);
      acc = fmaf(tanh_fast(hw.w + hr.w), wn0.w, acc);
      hw = whp[1]; hr = rhp[1];
      acc = fmaf(tanh_fast(hw.x + hr.x), wn1.x, acc);
      acc = fmaf(tanh_fast(hw.y + hr.y), wn1.y, acc);
      acc = fmaf(tanh_fast(hw.z + hr.z), wn1.z, acc);
      acc = fmaf(tanh_fast(hw.w + hr.w), wn1.w, acc);
      hw = whp[2]; hr = rhp[2];
      acc = fmaf(tanh_fast(hw.x + hr.x), wn2.x, acc);
      acc = fmaf(tanh_fast(hw.y + hr.y), wn2.y, acc);
      acc = fmaf(tanh_fast(hw.z + hr.z), wn2.z, acc);
      acc = fmaf(tanh_fast(hw.w + hr.w), wn2.w, acc);
      hw = whp[3]; hr = rhp[3];
      acc = fmaf(tanh_fast(hw.x + hr.x), wn3.x, acc);
      acc = fmaf(tanh_fast(hw.y + hr.y), wn3.y, acc);
      acc = fmaf(tanh_fast(hw.z + hr.z), wn3.z, acc);
      acc = fmaf(tanh_fast(hw.w + hr.w), wn3.w, acc);
      acc += __shfl_xor(acc, 1);
      acc += __shfl_xor(acc, 2);
      acc += __shfl_xor(acc, 4);
      acc += __shfl_xor(acc, 8);
      if (gl == 0) {
        float s = sigmoid_fast(acc + bias);  // relu(sigmoid) == sigmoid
        atomicAdd(&nst[bt], s);
        atomicAdd(&nsr[(size_t)b * R_ + r], s);
      }
    }
  }
  grid_barrier(bar, 2u * NBLK);

  // ========================= stage C: aggregates ==========================
  {
    int b = bid >> 3, dc = bid & 7;  // exactly 256 vblocks
    int dl = tid & 63, ts = tid >> 6;
    int d = dc * 64 + dl;
    if (tid < T_) {
      psc_s[tid] = pscore[b * T_ + tid];
      nst_s[tid] = nst[b * T_ + tid];
    } else if (tid < T_ + R_) {
      nsr_s[tid - T_] = nsr[b * R_ + (tid - T_)];
    }
    __syncthreads();
    float na = 0.f, pa = 0.f;
    for (int t = ts; t < T_; t += 8) {
      size_t base = ((size_t)(b * T_ + t)) * D_ + d;
      na = fmaf(nst_s[t], word[base], na);
      pa = fmaf(psc_s[t], pos[base], pa);
    }
    for (int r = ts; r < R_; r += 8)
      na = fmaf(nsr_s[r], region[((size_t)(b * R_ + r)) * D_ + d], na);
    redn[ts][dl] = na;
    redp[ts][dl] = pa;
    __syncthreads();
    if (tid < 64) {
      float s = 0.f;
#pragma unroll
      for (int k = 0; k < 8; ++k) s += redn[k][tid];
      nagg[(size_t)b * D_ + dc * 64 + tid] = s;
    } else if (tid < 128) {
      int l = tid - 64;
      float s = 0.f;
#pragma unroll
      for (int k = 0; k < 8; ++k) s += redp[k][l];
      pagg[(size_t)b * D_ + dc * 64 + l] = s;
    }
  }
  grid_barrier(bar, 3u * NBLK);

  // ========================= stage D: per-b tail ==========================
  if (bid < B_) {
    int b = bid;
    float cntp = (tid < T_) ? negcnt[b * T_ + tid] : 0.f;
    float cw = wave_sum(cntp);
    if (lane == 0) red[wave] = cw;  // waves 2..7 write 0
    int d = tid;  // 512 threads cover D
    float n0 = nagg[(size_t)b * D_ + d], p0 = pagg[(size_t)b * D_ + d];
    na_s[d] = n0;
    pa_s[d] = p0;
    __syncthreads();
    float cnt_total = 0.f;
#pragma unroll
    for (int w = 0; w < 8; ++w) cnt_total += red[w];
    float f = fcw[d];
    float c0p = n0 * f, c1p = p0 * f;
    c0p = wave_sum(c0p);
    c1p = wave_sum(c1p);
    __syncthreads();
    if (lane == 0) { red[wave] = c0p; red[wave + 8] = c1p; }
    __syncthreads();
    if (tid == 0) {
      float c0 = fcb[0], c1 = fcb[0];
#pragma unroll
      for (int w = 0; w < 8; ++w) { c0 += red[w]; c1 += red[w + 8]; }
      if (cnt_total == 0.f) c0 = -1e9f;
      float m = fmaxf(c0, c1);
      float e0 = __expf(c0 - m), e1 = __expf(c1 - m);
      float inv = 1.f / (e0 + e1);
      pp_s[0] = e0 * inv;
      pp_s[1] = e1 * inv;
      out[2 * B_ + 2 * b + 0] = pp_s[0];
      out[2 * B_ + 2 * b + 1] = pp_s[1];
    }
    __syncthreads();
    fin[d] = pp_s[0] * na_s[d] + pp_s[1] * pa_s[d];
    __syncthreads();
    // classifier matvec: 2 threads per column, 4-way split accumulators
    int c2 = tid >> 1, h = tid & 1;
    int dbase = h * 256;
    float a0 = 0.f, a1 = 0.f, a2 = 0.f, a3 = 0.f;
#pragma unroll 4
    for (int dd = 0; dd < 256; dd += 4) {
      a0 = fmaf(fin[dbase + dd + 0], cw1[(size_t)(dbase + dd + 0) * HC_ + c2], a0);
      a1 = fmaf(fin[dbase + dd + 1], cw1[(size_t)(dbase + dd + 1) * HC_ + c2], a1);
      a2 = fmaf(fin[dbase + dd + 2], cw1[(size_t)(dbase + dd + 2) * HC_ + c2], a2);
      a3 = fmaf(fin[dbase + dd + 3], cw1[(size_t)(dbase + dd + 3) * HC_ + c2], a3);
    }
    float ap = (a0 + a1) + (a2 + a3);
    ap += __shfl_xor(ap, 1);  // combine the two halves of the d-range
    float full = fmaxf(ap + cb1[c2], 0.f);
    float l0 = (h == 0) ? full * cw2[2 * c2 + 0] : 0.f;
    float l1 = (h == 0) ? full * cw2[2 * c2 + 1] : 0.f;
    l0 = wave_sum(l0);
    l1 = wave_sum(l1);
    __syncthreads();
    if (lane == 0) { red[wave] = l0; red[wave + 8] = l1; }
    __syncthreads();
    if (tid == 0) {
      float s0 = cb2[0], s1 = cb2[1];
#pragma unroll
      for (int w = 0; w < 8; ++w) { s0 += red[w]; s1 += red[w + 8]; }
      out[2 * b + 0] = s0;
      out[2 * b + 1] = s1;
    }
  }
}

extern "C" void kernel_launch(void* const* d_in, const int* in_sizes, int n_in,
                              void* d_out, int out_size, void* d_ws,
                              size_t ws_size, hipStream_t stream) {
  const float* word = (const float*)d_in[0];
  const float* region = (const float*)d_in[1];
  const int* amask = (const int*)d_in[2];
  const float* pw1 = (const float*)d_in[3];
  const float* pb1 = (const float*)d_in[4];
  const float* pw2 = (const float*)d_in[5];
  const float* pb2 = (const float*)d_in[6];
  const float* nw1 = (const float*)d_in[7];
  const float* nb1 = (const float*)d_in[8];
  const float* nw2 = (const float*)d_in[9];
  const float* nb2 = (const float*)d_in[10];
  const float* fcw = (const float*)d_in[11];
  const float* fcb = (const float*)d_in[12];
  const float* cw1 = (const float*)d_in[13];
  const float* cb1 = (const float*)d_in[14];
  const float* cw2 = (const float*)d_in[15];
  const float* cb2 = (const float*)d_in[16];
  float* out = (float*)d_out;

  unsigned short* wpack = (unsigned short*)d_ws;  // 2*131072 bf16 = 512 KB
  float* ws = (float*)d_ws + 131072;
  float* pos = ws;                              // B*T*D
  float* wh = pos + (size_t)B_ * T_ * D_;       // B*T*HE
  float* rh = wh + (size_t)B_ * T_ * HE_;       // B*R*HE
  float* nst = rh + (size_t)B_ * R_ * HE_;      // B*T  (neg-score sum over r)
  float* nsr = nst + (size_t)B_ * T_;           // B*R  (neg-score sum over t)
  float* negcnt = nsr + (size_t)B_ * R_;        // B*T
  float* pscore = negcnt + B_ * T_;             // B*T
  float* nagg = pscore + B_ * T_;               // B*D
  float* pagg = nagg + (size_t)B_ * D_;         // B*D
  unsigned* list = (unsigned*)(pagg + (size_t)B_ * D_);  // B*T*R
  unsigned* counter = list + (size_t)B_ * T_ * R_;       // [0] = compaction
  unsigned* bar = counter + 64;                          // [0] = grid barrier

  pack_w<<<128, 256, 0, stream>>>(nw1, pw1, wpack, counter, bar, nst, nsr);
  mega<<<NBLK, 512, 0, stream>>>(word, region, wpack, nb1, amask, pb1, pw2,
                                 pb2, nw2, nb2, fcw, fcb, cw1, cb1, cw2, cb2,
                                 wh, rh, pos, negcnt, list, counter, pscore,
                                 nst, nsr, nagg, pagg, bar, out);
}

// Round 3
// 171.156 us; speedup vs baseline: 2.2038x; 2.2038x over previous
//
#include <hip/hip_runtime.h>

#define B_ 32
#define T_ 128
#define R_ 49
#define D_ 512
#define HE_ 256
#define HC_ 256

#define NBLK 256       // persistent grid: 1 block/CU, guaranteed co-resident
#define NG_GEMM1 354   // 256 wh-tiles + 98 rh-tiles
#define NG_K1 512      // 8 tokens per virtual block

typedef float f32x4 __attribute__((ext_vector_type(4)));
typedef short s16x8 __attribute__((ext_vector_type(8)));
typedef short s16x4 __attribute__((ext_vector_type(4)));

__device__ __forceinline__ unsigned short bf16rne(float f) {
  unsigned u = __float_as_uint(f);
  u += 0x7FFF + ((u >> 16) & 1);
  return (unsigned short)(u >> 16);
}
__device__ __forceinline__ float rcp_fast(float x) {
  return __builtin_amdgcn_rcpf(x);
}
__device__ __forceinline__ float tanh_fast(float x) {
  float e = __expf(2.0f * x);
  return fmaf(-2.0f, rcp_fast(e + 1.0f), 1.0f);
}
__device__ __forceinline__ float sigmoid_fast(float x) {
  return rcp_fast(1.0f + __expf(-x));
}
__device__ __forceinline__ float wave_sum(float v) {
#pragma unroll
  for (int off = 32; off; off >>= 1) v += __shfl_down(v, off);
  return v;  // total valid in lane 0
}

// Device-scope grid barrier (fixed from R2). Key change: the spin uses
// RELAXED atomic loads — R2 polled with ACQUIRE, which on gfx950 emits a
// buffer_inv (L1/L2 invalidate) EVERY iteration, thrashing the XCD caches
// of still-working blocks (measured: 2.3% HBM bw, 2x FETCH_SIZE, 377us).
// Fence work is now exactly once per block per barrier:
//   __syncthreads()        -> all waves' global writes drained to L2
//   RELEASE fetch_add      -> one wbl2 (flush local L2 cross-XCD)
//   RELAXED polls          -> sc1 reads, no cache invalidation
//   one ACQUIRE load       -> one buffer_inv before consuming remote data
// Safe: grid == NBLK == 256 == #CUs, so every block is resident.
__device__ __forceinline__ void grid_barrier(unsigned* bar, unsigned target,
                                             bool wait) {
  __syncthreads();
  if (threadIdx.x == 0) {
    __hip_atomic_fetch_add(bar, 1u, __ATOMIC_RELEASE,
                           __HIP_MEMORY_SCOPE_AGENT);
    if (wait) {
      while (__hip_atomic_load(bar, __ATOMIC_RELAXED,
                               __HIP_MEMORY_SCOPE_AGENT) < target)
        __builtin_amdgcn_s_sleep(4);
      (void)__hip_atomic_load(bar, __ATOMIC_ACQUIRE,
                              __HIP_MEMORY_SCOPE_AGENT);
    }
  }
  __syncthreads();
}

// ---------------------------------------------------------------------------
// pack_w: repack nw1 (mat0) and pw1 (mat1) [512][256] fp32 -> bf16 B-fragment
// order [mat][kt16][ct16][lane64][j8]. Also zeroes counter, grid-barrier
// counter, and the nst/nsr marginals (graph-replay-safe re-init each call).
// ---------------------------------------------------------------------------
__global__ __launch_bounds__(256) void pack_w(
    const float* __restrict__ nw1, const float* __restrict__ pw1,
    unsigned short* __restrict__ wp, unsigned* __restrict__ counter,
    unsigned* __restrict__ bar, float* __restrict__ nst,
    float* __restrict__ nsr) {
  int gid = blockIdx.x * 256 + threadIdx.x;  // 0..32767
  if (gid == 0) { counter[0] = 0u; bar[0] = 0u; }
  if (gid < B_ * T_) nst[gid] = 0.f;
  if (gid < B_ * R_) nsr[gid] = 0.f;
  int mat = gid >> 14;
  int rem = gid & 16383;
  int lane = rem & 63;
  int tile = rem >> 6;
  int kt = tile >> 4, ct = tile & 15;
  const float* W = mat ? pw1 : nw1;
  int k0 = kt * 32 + (lane >> 4) * 8;
  int c = ct * 16 + (lane & 15);
  s16x8 pk;
#pragma unroll
  for (int j = 0; j < 8; ++j)
    pk[j] = (short)bf16rne(W[(size_t)(k0 + j) * HE_ + c]);
  *(s16x8*)(wp + (size_t)gid * 8) = pk;
}

// ---------------------------------------------------------------------------
// mega: persistent fused pipeline.
//   stage A: {wh,rh} MFMA-GEMM + k1 attn/softmax/pos/compaction
//   stage B: hp=pos@pw1 + pscore  |  neg-expert over compacted list -> nst/nsr
//   stage C: per-(b,dchunk) aggregates nagg/pagg
//   stage D: per-b tail (choose/path_prob/final/classifier)
// Grid barriers between stages replace 3 kernel-launch boundaries.
// ---------------------------------------------------------------------------
__global__ __launch_bounds__(512) void mega(
    const float* __restrict__ word, const float* __restrict__ region,
    const unsigned short* __restrict__ wpack, const float* __restrict__ nb1,
    const int* __restrict__ amask, const float* __restrict__ pb1,
    const float* __restrict__ pw2, const float* __restrict__ pb2,
    const float* __restrict__ nw2, const float* __restrict__ nb2,
    const float* __restrict__ fcw, const float* __restrict__ fcb,
    const float* __restrict__ cw1, const float* __restrict__ cb1,
    const float* __restrict__ cw2, const float* __restrict__ cb2,
    float* __restrict__ wh, float* __restrict__ rh, float* __restrict__ pos,
    float* __restrict__ negcnt, unsigned* __restrict__ list,
    unsigned* __restrict__ counter, float* __restrict__ pscore,
    float* __restrict__ nst, float* __restrict__ nsr,
    float* __restrict__ nagg, float* __restrict__ pagg,
    unsigned* __restrict__ bar, float* __restrict__ out) {
  __shared__ alignas(16) unsigned short As[16 * 512];  // also hp_s fp32[16][256]
  __shared__ float attn_s[8][52];
  __shared__ alignas(16) float wp_T[49][8];
  __shared__ int wcnt_s[8];
  __shared__ int woff_s[8];
  __shared__ unsigned base_s;
  __shared__ float sred[16][4];
  __shared__ float nst_s[T_], psc_s[T_], nsr_s[R_];
  __shared__ float redn[8][64], redp[8][64];
  __shared__ float na_s[D_], pa_s[D_], fin[D_];
  __shared__ float red[16];
  __shared__ float pp_s[2];

  int tid = threadIdx.x, wave = tid >> 6, lane = tid & 63;
  int bid = blockIdx.x;

  // ======================= stage A: m1 GEMM + k1 ==========================
  for (int vb = bid; vb < NG_GEMM1 + NG_K1; vb += NBLK) {
    __syncthreads();  // LDS reuse guard between virtual blocks
    if (vb < NG_GEMM1) {
      const float* A;
      float* outp;
      int row0;
      bool useb;
      if (vb < 256) {
        A = word; outp = wh; row0 = vb * 16; useb = true;
      } else {
        A = region; outp = rh; row0 = (vb - 256) * 16; useb = false;
      }
      const float4* A4 = (const float4*)(A + (size_t)row0 * D_);
#pragma unroll
      for (int it = 0; it < 4; ++it) {
        int f = it * 512 + tid;
        int row = f >> 7, kq = f & 127;
        float4 v = A4[f];
        int bo = (row * 1024 + kq * 8) ^ ((row & 7) << 4);
        s16x4 pk;
        pk[0] = (short)bf16rne(v.x);
        pk[1] = (short)bf16rne(v.y);
        pk[2] = (short)bf16rne(v.z);
        pk[3] = (short)bf16rne(v.w);
        *(s16x4*)((char*)As + bo) = pk;
      }
      __syncthreads();
      int rl = lane & 15, kg = lane >> 4;
      f32x4 acc0 = {0.f, 0.f, 0.f, 0.f}, acc1 = {0.f, 0.f, 0.f, 0.f};
      const s16x8* Wp8 = (const s16x8*)wpack;  // mat 0 = nw1
      int ct0 = wave, ct1 = wave + 8;
#pragma unroll
      for (int kt = 0; kt < 16; ++kt) {
        int bo = (rl * 1024 + kt * 64 + kg * 16) ^ ((rl & 7) << 4);
        s16x8 af = *(const s16x8*)((char*)As + bo);
        s16x8 b0 = Wp8[(size_t)(kt * 16 + ct0) * 64 + lane];
        s16x8 b1 = Wp8[(size_t)(kt * 16 + ct1) * 64 + lane];
        acc0 = __builtin_amdgcn_mfma_f32_16x16x32_bf16(af, b0, acc0, 0, 0, 0);
        acc1 = __builtin_amdgcn_mfma_f32_16x16x32_bf16(af, b1, acc1, 0, 0, 0);
      }
      // C/D layout (m89-verified): col = lane&15, row = (lane>>4)*4 + reg
      float bb0 = useb ? nb1[ct0 * 16 + rl] : 0.f;
      float bb1 = useb ? nb1[ct1 * 16 + rl] : 0.f;
      int r0 = row0 + kg * 4;
#pragma unroll
      for (int q = 0; q < 4; ++q) {
        outp[(size_t)(r0 + q) * HE_ + ct0 * 16 + rl] = acc0[q] + bb0;
        outp[(size_t)(r0 + q) * HE_ + ct1 * 16 + rl] = acc1[q] + bb1;
      }
    } else {
      // ---- k1: 8 tokens, fp32 (hard threshold at 0.1 needs fp32 attn)
      int bid2 = vb - NG_GEMM1;
      int b = bid2 >> 4;
      int t0 = (bid2 & 15) * 8;
      int bt0 = b * T_ + t0;
      const float* reg = region + (size_t)b * R_ * D_;

      const float4* word4 = (const float4*)word;
      float4 wv[8][2];
#pragma unroll
      for (int t = 0; t < 8; ++t)
#pragma unroll
        for (int j = 0; j < 2; ++j)
          wv[t][j] = word4[(size_t)(bt0 + t) * 128 + lane * 2 + j];

      for (int r = wave; r < R_; r += 8) {
        const float4* rrow4 = (const float4*)(reg + (size_t)r * D_);
        float4 rv0 = rrow4[lane * 2 + 0];
        float4 rv1 = rrow4[lane * 2 + 1];
#pragma unroll
        for (int t = 0; t < 8; ++t) {
          float4 w0 = wv[t][0], w1 = wv[t][1];
          float acc = 0.f;
          acc = fmaf(w0.x, rv0.x, acc);
          acc = fmaf(w0.y, rv0.y, acc);
          acc = fmaf(w0.z, rv0.z, acc);
          acc = fmaf(w0.w, rv0.w, acc);
          acc = fmaf(w1.x, rv1.x, acc);
          acc = fmaf(w1.y, rv1.y, acc);
          acc = fmaf(w1.z, rv1.z, acc);
          acc = fmaf(w1.w, rv1.w, acc);
          acc = wave_sum(acc);
          if (lane == 0) attn_s[t][r] = acc;
        }
      }
      __syncthreads();

      bool want;
      unsigned long long bm;
      {
        int t = wave;  // 8 waves, one token each
        int am = amask[bt0 + t];
        float a = (lane < R_) ? attn_s[t][lane] : 0.f;
        float neg = (lane < R_ && (a - 0.1f) > 0.f) ? 1.f : 0.f;
        float masked =
            (lane < R_) ? ((neg > 0.f) ? a * 4.0f : -4e9f) : -3.0e38f;
        float cnt = wave_sum(neg);
        float m = masked;
#pragma unroll
        for (int off = 32; off; off >>= 1) m = fmaxf(m, __shfl_down(m, off));
        m = __shfl(m, 0);
        float e = (lane < R_) ? __expf(masked - m) : 0.f;
        float s = wave_sum(e);
        s = __shfl(s, 0);
        if (lane < R_) wp_T[lane][t] = e / s;
        if (lane == 0) negcnt[bt0 + t] = cnt;
        want = (lane < R_) && (neg == 0.f) && (am != 0);
        bm = __ballot(want);
        if (lane == 0) wcnt_s[wave] = __popcll(bm);
      }
      __syncthreads();
      if (tid == 0) {
        int tot = 0;
#pragma unroll
        for (int w = 0; w < 8; ++w) { woff_s[w] = tot; tot += wcnt_s[w]; }
        base_s = atomicAdd(counter, (unsigned)tot);  // ONE atomic per vblock
      }
      __syncthreads();
      if (want) {
        int prefix = __popcll(bm & ((1ull << lane) - 1ull));
        list[base_s + (unsigned)woff_s[wave] + (unsigned)prefix] =
            (unsigned)((bt0 + wave) * R_ + lane);
      }

      // pos: thread owns d = tid (512 = D), 8 token accumulators
      int d = tid;
      float accs[8] = {0.f, 0.f, 0.f, 0.f, 0.f, 0.f, 0.f, 0.f};
#pragma unroll 7
      for (int r = 0; r < R_; ++r) {
        float g = reg[(size_t)r * D_ + d];
        float4 w0 = *(const float4*)&wp_T[r][0];
        float4 w1 = *(const float4*)&wp_T[r][4];
        accs[0] = fmaf(w0.x, g, accs[0]);
        accs[1] = fmaf(w0.y, g, accs[1]);
        accs[2] = fmaf(w0.z, g, accs[2]);
        accs[3] = fmaf(w0.w, g, accs[3]);
        accs[4] = fmaf(w1.x, g, accs[4]);
        accs[5] = fmaf(w1.y, g, accs[5]);
        accs[6] = fmaf(w1.z, g, accs[6]);
        accs[7] = fmaf(w1.w, g, accs[7]);
      }
#pragma unroll
      for (int t = 0; t < 8; ++t) {
        size_t base = (size_t)(bt0 + t) * D_ + d;
        pos[base] = word[base] + accs[t];
      }
    }
  }
  grid_barrier(bar, NBLK, true);

  // ================= stage B: m2 GEMM (pscore) + neg-expert ===============
  {
    int row0 = bid * 16;  // exactly 256 tiles over 256 blocks
    const float4* A4 = (const float4*)(pos + (size_t)row0 * D_);
#pragma unroll
    for (int it = 0; it < 4; ++it) {
      int f = it * 512 + tid;
      int row = f >> 7, kq = f & 127;
      float4 v = A4[f];
      int bo = (row * 1024 + kq * 8) ^ ((row & 7) << 4);
      s16x4 pk;
      pk[0] = (short)bf16rne(v.x);
      pk[1] = (short)bf16rne(v.y);
      pk[2] = (short)bf16rne(v.z);
      pk[3] = (short)bf16rne(v.w);
      *(s16x4*)((char*)As + bo) = pk;
    }
    __syncthreads();
    int rl = lane & 15, kg = lane >> 4;
    f32x4 acc0 = {0.f, 0.f, 0.f, 0.f}, acc1 = {0.f, 0.f, 0.f, 0.f};
    const s16x8* Wp8 = (const s16x8*)wpack + 16384;  // mat 1 = pw1
    int ct0 = wave, ct1 = wave + 8;
#pragma unroll
    for (int kt = 0; kt < 16; ++kt) {
      int bo = (rl * 1024 + kt * 64 + kg * 16) ^ ((rl & 7) << 4);
      s16x8 af = *(const s16x8*)((char*)As + bo);
      s16x8 b0 = Wp8[(size_t)(kt * 16 + ct0) * 64 + lane];
      s16x8 b1 = Wp8[(size_t)(kt * 16 + ct1) * 64 + lane];
      acc0 = __builtin_amdgcn_mfma_f32_16x16x32_bf16(af, b0, acc0, 0, 0, 0);
      acc1 = __builtin_amdgcn_mfma_f32_16x16x32_bf16(af, b1, acc1, 0, 0, 0);
    }
    __syncthreads();  // all A-tile reads done; reuse LDS for hp
    float* hp_s = (float*)As;  // [16][256] fp32 = 16 KB
#pragma unroll
    for (int q = 0; q < 4; ++q) {
      hp_s[(kg * 4 + q) * 256 + ct0 * 16 + rl] = acc0[q];
      hp_s[(kg * 4 + q) * 256 + ct1 * 16 + rl] = acc1[q];
    }
    __syncthreads();
    int c = tid & 255, jh = tid >> 8;  // wave w covers c-chunk (w&3), jh=w>>2
    float pb1c = pb1[c], pw2c = pw2[c];
#pragma unroll
    for (int jj = 0; jj < 8; ++jj) {
      int j = jh * 8 + jj;
      float v = tanh_fast(hp_s[j * 256 + c] + pb1c) * pw2c;
      v = wave_sum(v);
      if (lane == 0) sred[j][wave & 3] = v;
    }
    __syncthreads();
    if (tid < 16) {
      float s = sred[tid][0] + sred[tid][1] + sred[tid][2] + sred[tid][3] +
                pb2[0];
      s = sigmoid_fast(s);
      int row = row0 + tid;
      if (negcnt[row] == 0.f) s = 0.f;
      s *= (float)amask[row];
      pscore[row] = fmaxf(s, 0.f);
    }
  }
  {
    // neg-expert over compacted list: 16-lane group per pair, grid-stride
    int grp = tid >> 4, gl = tid & 15;
    unsigned count = counter[0];  // finalized at stage-A barrier
    const float4* n4 = (const float4*)(nw2 + gl * 16);
    float4 wn0 = n4[0], wn1 = n4[1], wn2 = n4[2], wn3 = n4[3];
    float bias = nb2[0];
    for (unsigned i = (unsigned)bid * 32u + (unsigned)grp; i < count;
         i += (unsigned)NBLK * 32u) {
      unsigned pair = list[i];
      int bt = (int)(pair / R_);
      int r = (int)(pair - (unsigned)bt * R_);
      int b = bt >> 7;
      const float4* whp = (const float4*)(wh + (size_t)bt * HE_ + gl * 16);
      const float4* rhp =
          (const float4*)(rh + ((size_t)b * R_ + r) * HE_ + gl * 16);
      float acc = 0.f;
      float4 hw, hr;
      hw = whp[0]; hr = rhp[0];
      acc = fmaf(tanh_fast(hw.x + hr.x), wn0.x, acc);
      acc = fmaf(tanh_fast(hw.y + hr.y), wn0.y, acc);
      acc = fmaf(tanh_fast(hw.z + hr.z), wn0.z, acc);
      acc = fmaf(tanh_fast(hw.w + hr.w), wn0.w, acc);
      hw = whp[1]; hr = rhp[1];
      acc = fmaf(tanh_fast(hw.x + hr.x), wn1.x, acc);
      acc = fmaf(tanh_fast(hw.y + hr.y), wn1.y, acc);
      acc = fmaf(tanh_fast(hw.z + hr.z), wn1.z, acc);
      acc = fmaf(tanh_fast(hw.w + hr.w), wn1.w, acc);
      hw = whp[2]; hr = rhp[2];
      acc = fmaf(tanh_fast(hw.x + hr.x), wn2.x, acc);
      acc = fmaf(tanh_fast(hw.y + hr.y), wn2.y, acc);
      acc = fmaf(tanh_fast(hw.z + hr.z), wn2.z, acc);
      acc = fmaf(tanh_fast(hw.w + hr.w), wn2.w, acc);
      hw = whp[3]; hr = rhp[3];
      acc = fmaf(tanh_fast(hw.x + hr.x), wn3.x, acc);
      acc = fmaf(tanh_fast(hw.y + hr.y), wn3.y, acc);
      acc = fmaf(tanh_fast(hw.z + hr.z), wn3.z, acc);
      acc = fmaf(tanh_fast(hw.w + hr.w), wn3.w, acc);
      acc += __shfl_xor(acc, 1);
      acc += __shfl_xor(acc, 2);
      acc += __shfl_xor(acc, 4);
      acc += __shfl_xor(acc, 8);
      if (gl == 0) {
        float s = sigmoid_fast(acc + bias);  // relu(sigmoid) == sigmoid
        atomicAdd(&nst[bt], s);
        atomicAdd(&nsr[(size_t)b * R_ + r], s);
      }
    }
  }
  grid_barrier(bar, 2u * NBLK, true);

  // ========================= stage C: aggregates ==========================
  {
    int b = bid >> 3, dc = bid & 7;  // exactly 256 vblocks
    int dl = tid & 63, ts = tid >> 6;
    int d = dc * 64 + dl;
    if (tid < T_) {
      psc_s[tid] = pscore[b * T_ + tid];
      nst_s[tid] = nst[b * T_ + tid];
    } else if (tid < T_ + R_) {
      nsr_s[tid - T_] = nsr[b * R_ + (tid - T_)];
    }
    __syncthreads();
    float na = 0.f, pa = 0.f;
    for (int t = ts; t < T_; t += 8) {
      size_t base = ((size_t)(b * T_ + t)) * D_ + d;
      na = fmaf(nst_s[t], word[base], na);
      pa = fmaf(psc_s[t], pos[base], pa);
    }
    for (int r = ts; r < R_; r += 8)
      na = fmaf(nsr_s[r], region[((size_t)(b * R_ + r)) * D_ + d], na);
    redn[ts][dl] = na;
    redp[ts][dl] = pa;
    __syncthreads();
    if (tid < 64) {
      float s = 0.f;
#pragma unroll
      for (int k = 0; k < 8; ++k) s += redn[k][tid];
      nagg[(size_t)b * D_ + dc * 64 + tid] = s;
    } else if (tid < 128) {
      int l = tid - 64;
      float s = 0.f;
#pragma unroll
      for (int k = 0; k < 8; ++k) s += redp[k][l];
      pagg[(size_t)b * D_ + dc * 64 + l] = s;
    }
  }
  grid_barrier(bar, 3u * NBLK, bid < B_);  // non-tail blocks arrive + exit

  // ========================= stage D: per-b tail ==========================
  if (bid < B_) {
    int b = bid;
    float cntp = (tid < T_) ? negcnt[b * T_ + tid] : 0.f;
    float cw = wave_sum(cntp);
    if (lane == 0) red[wave] = cw;  // waves 2..7 write 0
    int d = tid;  // 512 threads cover D
    float n0 = nagg[(size_t)b * D_ + d], p0 = pagg[(size_t)b * D_ + d];
    na_s[d] = n0;
    pa_s[d] = p0;
    __syncthreads();
    float cnt_total = 0.f;
#pragma unroll
    for (int w = 0; w < 8; ++w) cnt_total += red[w];
    float f = fcw[d];
    float c0p = n0 * f, c1p = p0 * f;
    c0p = wave_sum(c0p);
    c1p = wave_sum(c1p);
    __syncthreads();
    if (lane == 0) { red[wave] = c0p; red[wave + 8] = c1p; }
    __syncthreads();
    if (tid == 0) {
      float c0 = fcb[0], c1 = fcb[0];
#pragma unroll
      for (int w = 0; w < 8; ++w) { c0 += red[w]; c1 += red[w + 8]; }
      if (cnt_total == 0.f) c0 = -1e9f;
      float m = fmaxf(c0, c1);
      float e0 = __expf(c0 - m), e1 = __expf(c1 - m);
      float inv = 1.f / (e0 + e1);
      pp_s[0] = e0 * inv;
      pp_s[1] = e1 * inv;
      out[2 * B_ + 2 * b + 0] = pp_s[0];
      out[2 * B_ + 2 * b + 1] = pp_s[1];
    }
    __syncthreads();
    fin[d] = pp_s[0] * na_s[d] + pp_s[1] * pa_s[d];
    __syncthreads();
    // classifier matvec: 2 threads per column, 4-way split accumulators
    int c2 = tid >> 1, h = tid & 1;
    int dbase = h * 256;
    float a0 = 0.f, a1 = 0.f, a2 = 0.f, a3 = 0.f;
#pragma unroll 4
    for (int dd = 0; dd < 256; dd += 4) {
      a0 = fmaf(fin[dbase + dd + 0], cw1[(size_t)(dbase + dd + 0) * HC_ + c2], a0);
      a1 = fmaf(fin[dbase + dd + 1], cw1[(size_t)(dbase + dd + 1) * HC_ + c2], a1);
      a2 = fmaf(fin[dbase + dd + 2], cw1[(size_t)(dbase + dd + 2) * HC_ + c2], a2);
      a3 = fmaf(fin[dbase + dd + 3], cw1[(size_t)(dbase + dd + 3) * HC_ + c2], a3);
    }
    float ap = (a0 + a1) + (a2 + a3);
    ap += __shfl_xor(ap, 1);  // combine the two halves of the d-range
    float full = fmaxf(ap + cb1[c2], 0.f);
    float l0 = (h == 0) ? full * cw2[2 * c2 + 0] : 0.f;
    float l1 = (h == 0) ? full * cw2[2 * c2 + 1] : 0.f;
    l0 = wave_sum(l0);
    l1 = wave_sum(l1);
    __syncthreads();
    if (lane == 0) { red[wave] = l0; red[wave + 8] = l1; }
    __syncthreads();
    if (tid == 0) {
      float s0 = cb2[0], s1 = cb2[1];
#pragma unroll
      for (int w = 0; w < 8; ++w) { s0 += red[w]; s1 += red[w + 8]; }
      out[2 * b + 0] = s0;
      out[2 * b + 1] = s1;
    }
  }
}

extern "C" void kernel_launch(void* const* d_in, const int* in_sizes, int n_in,
                              void* d_out, int out_size, void* d_ws,
                              size_t ws_size, hipStream_t stream) {
  const float* word = (const float*)d_in[0];
  const float* region = (const float*)d_in[1];
  const int* amask = (const int*)d_in[2];
  const float* pw1 = (const float*)d_in[3];
  const float* pb1 = (const float*)d_in[4];
  const float* pw2 = (const float*)d_in[5];
  const float* pb2 = (const float*)d_in[6];
  const float* nw1 = (const float*)d_in[7];
  const float* nb1 = (const float*)d_in[8];
  const float* nw2 = (const float*)d_in[9];
  const float* nb2 = (const float*)d_in[10];
  const float* fcw = (const float*)d_in[11];
  const float* fcb = (const float*)d_in[12];
  const float* cw1 = (const float*)d_in[13];
  const float* cb1 = (const float*)d_in[14];
  const float* cw2 = (const float*)d_in[15];
  const float* cb2 = (const float*)d_in[16];
  float* out = (float*)d_out;

  unsigned short* wpack = (unsigned short*)d_ws;  // 2*131072 bf16 = 512 KB
  float* ws = (float*)d_ws + 131072;
  float* pos = ws;                              // B*T*D
  float* wh = pos + (size_t)B_ * T_ * D_;       // B*T*HE
  float* rh = wh + (size_t)B_ * T_ * HE_;       // B*R*HE
  float* nst = rh + (size_t)B_ * R_ * HE_;      // B*T  (neg-score sum over r)
  float* nsr = nst + (size_t)B_ * T_;           // B*R  (neg-score sum over t)
  float* negcnt = nsr + (size_t)B_ * R_;        // B*T
  float* pscore = negcnt + B_ * T_;             // B*T
  float* nagg = pscore + B_ * T_;               // B*D
  float* pagg = nagg + (size_t)B_ * D_;         // B*D
  unsigned* list = (unsigned*)(pagg + (size_t)B_ * D_);  // B*T*R
  unsigned* counter = list + (size_t)B_ * T_ * R_;       // [0] = compaction
  unsigned* bar = counter + 64;                          // [0] = grid barrier

  pack_w<<<128, 256, 0, stream>>>(nw1, pw1, wpack, counter, bar, nst, nsr);
  mega<<<NBLK, 512, 0, stream>>>(word, region, wpack, nb1, amask, pb1, pw2,
                                 pb2, nw2, nb2, fcw, fcb, cw1, cb1, cw2, cb2,
                                 wh, rh, pos, negcnt, list, counter, pscore,
                                 nst, nsr, nagg, pagg, bar, out);
}

// Round 4
// 85.051 us; speedup vs baseline: 4.4349x; 2.0124x over previous
//
#include <hip/hip_runtime.h>

#define B_ 32
#define T_ 128
#define R_ 49
#define D_ 512
#define HE_ 256
#define HC_ 256

#define NG_GEMM1 354   // 256 wh-tiles + 98 rh-tiles
#define NG_K1 512      // 8 tokens per block
#define NG_GEMM2 256
#define NG_NEGB 512    // neg-expert: one block per (b, 8-token tile)

typedef float f32x4 __attribute__((ext_vector_type(4)));
typedef short s16x8 __attribute__((ext_vector_type(8)));
typedef short s16x4 __attribute__((ext_vector_type(4)));

__device__ __forceinline__ unsigned short bf16rne(float f) {
  unsigned u = __float_as_uint(f);
  u += 0x7FFF + ((u >> 16) & 1);
  return (unsigned short)(u >> 16);
}
__device__ __forceinline__ float rcp_fast(float x) {
  return __builtin_amdgcn_rcpf(x);
}
__device__ __forceinline__ float tanh_fast(float x) {
  float e = __expf(2.0f * x);
  return fmaf(-2.0f, rcp_fast(e + 1.0f), 1.0f);
}
__device__ __forceinline__ float sigmoid_fast(float x) {
  return rcp_fast(1.0f + __expf(-x));
}
__device__ __forceinline__ float wave_sum(float v) {
#pragma unroll
  for (int off = 32; off; off >>= 1) v += __shfl_down(v, off);
  return v;  // total valid in lane 0
}

// ---------------------------------------------------------------------------
// pack_w: repack nw1 (mat0) and pw1 (mat1) [512][256] fp32 -> bf16 B-fragment
// order [mat][kt16][ct16][lane64][j8]. Also zeroes the nsr marginal (the only
// remaining accumulate-into buffer; re-zeroed every call for graph replay).
// ---------------------------------------------------------------------------
__global__ __launch_bounds__(256) void pack_w(
    const float* __restrict__ nw1, const float* __restrict__ pw1,
    unsigned short* __restrict__ wp, float* __restrict__ nsr) {
  int gid = blockIdx.x * 256 + threadIdx.x;  // 0..32767
  if (gid < B_ * R_) nsr[gid] = 0.f;
  int mat = gid >> 14;
  int rem = gid & 16383;
  int lane = rem & 63;
  int tile = rem >> 6;
  int kt = tile >> 4, ct = tile & 15;
  const float* W = mat ? pw1 : nw1;
  int k0 = kt * 32 + (lane >> 4) * 8;
  int c = ct * 16 + (lane & 15);
  s16x8 pk;
#pragma unroll
  for (int j = 0; j < 8; ++j)
    pk[j] = (short)bf16rne(W[(size_t)(k0 + j) * HE_ + c]);
  *(s16x8*)(wp + (size_t)gid * 8) = pk;
}

// ---------------------------------------------------------------------------
// M1: fused {wh = word@nw1+nb1, rh = region@nw1} MFMA-GEMM + k1 (fp32 attn/
// softmax/pos, 8 tokens per block). Emits per-token active-region ballot
// masks (nmask) instead of a global compacted list.
// ---------------------------------------------------------------------------
__global__ __launch_bounds__(512) void m1_gemm_k1(
    const float* __restrict__ word, const float* __restrict__ region,
    const unsigned short* __restrict__ wpack, const float* __restrict__ nb1,
    const int* __restrict__ amask, float* __restrict__ wh,
    float* __restrict__ rh, float* __restrict__ pos,
    float* __restrict__ negcnt, unsigned long long* __restrict__ nmask) {
  __shared__ alignas(16) unsigned short As[16 * 512];
  __shared__ float attn_s[8][52];
  __shared__ alignas(16) float wp_T[49][8];
  int tid = threadIdx.x, wave = tid >> 6, lane = tid & 63;
  int bid = blockIdx.x;

  if (bid < NG_GEMM1) {
    const float* A;
    float* outp;
    int row0;
    bool useb;
    if (bid < 256) {
      A = word; outp = wh; row0 = bid * 16; useb = true;
    } else {
      A = region; outp = rh; row0 = (bid - 256) * 16; useb = false;
    }
    const float4* A4 = (const float4*)(A + (size_t)row0 * D_);
#pragma unroll
    for (int it = 0; it < 4; ++it) {
      int f = it * 512 + tid;
      int row = f >> 7, kq = f & 127;
      float4 v = A4[f];
      int bo = (row * 1024 + kq * 8) ^ ((row & 7) << 4);
      s16x4 pk;
      pk[0] = (short)bf16rne(v.x);
      pk[1] = (short)bf16rne(v.y);
      pk[2] = (short)bf16rne(v.z);
      pk[3] = (short)bf16rne(v.w);
      *(s16x4*)((char*)As + bo) = pk;
    }
    __syncthreads();
    int rl = lane & 15, kg = lane >> 4;
    f32x4 acc0 = {0.f, 0.f, 0.f, 0.f}, acc1 = {0.f, 0.f, 0.f, 0.f};
    const s16x8* Wp8 = (const s16x8*)wpack;  // mat 0 = nw1
    int ct0 = wave, ct1 = wave + 8;
#pragma unroll
    for (int kt = 0; kt < 16; ++kt) {
      int bo = (rl * 1024 + kt * 64 + kg * 16) ^ ((rl & 7) << 4);
      s16x8 af = *(const s16x8*)((char*)As + bo);
      s16x8 b0 = Wp8[(size_t)(kt * 16 + ct0) * 64 + lane];
      s16x8 b1 = Wp8[(size_t)(kt * 16 + ct1) * 64 + lane];
      acc0 = __builtin_amdgcn_mfma_f32_16x16x32_bf16(af, b0, acc0, 0, 0, 0);
      acc1 = __builtin_amdgcn_mfma_f32_16x16x32_bf16(af, b1, acc1, 0, 0, 0);
    }
    // C/D layout (m89-verified): col = lane&15, row = (lane>>4)*4 + reg
    float bb0 = useb ? nb1[ct0 * 16 + rl] : 0.f;
    float bb1 = useb ? nb1[ct1 * 16 + rl] : 0.f;
    int r0 = row0 + kg * 4;
#pragma unroll
    for (int q = 0; q < 4; ++q) {
      outp[(size_t)(r0 + q) * HE_ + ct0 * 16 + rl] = acc0[q] + bb0;
      outp[(size_t)(r0 + q) * HE_ + ct1 * 16 + rl] = acc1[q] + bb1;
    }
    return;
  }

  // ---- k1 branch: 8 tokens, fp32 (hard threshold at 0.1 needs fp32 attn)
  int bid2 = bid - NG_GEMM1;
  int b = bid2 >> 4;
  int t0 = (bid2 & 15) * 8;
  int bt0 = b * T_ + t0;
  const float* reg = region + (size_t)b * R_ * D_;

  // word rows as float4: lane holds elements 8*lane .. 8*lane+7
  const float4* word4 = (const float4*)word;
  float4 wv[8][2];
#pragma unroll
  for (int t = 0; t < 8; ++t)
#pragma unroll
    for (int j = 0; j < 2; ++j)
      wv[t][j] = word4[(size_t)(bt0 + t) * 128 + lane * 2 + j];

  for (int r = wave; r < R_; r += 8) {
    const float4* rrow4 = (const float4*)(reg + (size_t)r * D_);
    float4 rv0 = rrow4[lane * 2 + 0];
    float4 rv1 = rrow4[lane * 2 + 1];
#pragma unroll
    for (int t = 0; t < 8; ++t) {
      float4 w0 = wv[t][0], w1 = wv[t][1];
      float acc = 0.f;
      acc = fmaf(w0.x, rv0.x, acc);
      acc = fmaf(w0.y, rv0.y, acc);
      acc = fmaf(w0.z, rv0.z, acc);
      acc = fmaf(w0.w, rv0.w, acc);
      acc = fmaf(w1.x, rv1.x, acc);
      acc = fmaf(w1.y, rv1.y, acc);
      acc = fmaf(w1.z, rv1.z, acc);
      acc = fmaf(w1.w, rv1.w, acc);
      acc = wave_sum(acc);
      if (lane == 0) attn_s[t][r] = acc;
    }
  }
  __syncthreads();

  {
    int t = wave;  // 8 waves, one token each
    int am = amask[bt0 + t];
    float a = (lane < R_) ? attn_s[t][lane] : 0.f;
    float neg = (lane < R_ && (a - 0.1f) > 0.f) ? 1.f : 0.f;
    float masked = (lane < R_) ? ((neg > 0.f) ? a * 4.0f : -4e9f) : -3.0e38f;
    float cnt = wave_sum(neg);
    float m = masked;
#pragma unroll
    for (int off = 32; off; off >>= 1) m = fmaxf(m, __shfl_down(m, off));
    m = __shfl(m, 0);
    float e = (lane < R_) ? __expf(masked - m) : 0.f;
    float s = wave_sum(e);
    s = __shfl(s, 0);
    if (lane < R_) wp_T[lane][t] = e / s;
    bool want = (lane < R_) && (neg == 0.f) && (am != 0);
    unsigned long long bm = __ballot(want);
    if (lane == 0) {
      negcnt[bt0 + t] = cnt;
      nmask[bt0 + t] = bm;
    }
  }
  __syncthreads();

  // pos: thread owns d = tid (512 = D), 8 token accumulators
  int d = tid;
  float accs[8] = {0.f, 0.f, 0.f, 0.f, 0.f, 0.f, 0.f, 0.f};
#pragma unroll 7
  for (int r = 0; r < R_; ++r) {
    float g = reg[(size_t)r * D_ + d];
    float4 w0 = *(const float4*)&wp_T[r][0];
    float4 w1 = *(const float4*)&wp_T[r][4];
    accs[0] = fmaf(w0.x, g, accs[0]);
    accs[1] = fmaf(w0.y, g, accs[1]);
    accs[2] = fmaf(w0.z, g, accs[2]);
    accs[3] = fmaf(w0.w, g, accs[3]);
    accs[4] = fmaf(w1.x, g, accs[4]);
    accs[5] = fmaf(w1.y, g, accs[5]);
    accs[6] = fmaf(w1.z, g, accs[6]);
    accs[7] = fmaf(w1.w, g, accs[7]);
  }
#pragma unroll
  for (int t = 0; t < 8; ++t) {
    size_t base = (size_t)(bt0 + t) * D_ + d;
    pos[base] = word[base] + accs[t];
  }
}

// ---------------------------------------------------------------------------
// M2: fused {hp = pos@pw1 (MFMA, in-LDS) + pw2 score}  |  LDS-tiled neg-expert.
// Neg branch: block = (b, 8-token tile). rh[b] (49 KB) + wh rows (8 KB) staged
// in LDS ONCE; 16-lane groups compute active pairs from LDS with a chunk-
// rotation pattern (all 32 banks hit -> bank floor). Replaces the old per-pair
// 2 KB L2/L3 stream (~200 MB -> ~30 MB).
// ---------------------------------------------------------------------------
__global__ __launch_bounds__(512) void m2_hps_neg(
    const float* __restrict__ pos, const unsigned short* __restrict__ wpack,
    const float* __restrict__ pb1, const float* __restrict__ pw2,
    const float* __restrict__ pb2, const float* __restrict__ negcnt,
    const int* __restrict__ amask, const float* __restrict__ wh,
    const float* __restrict__ rh, const float* __restrict__ nw2,
    const float* __restrict__ nb2,
    const unsigned long long* __restrict__ nmask,
    float* __restrict__ pscore, float* __restrict__ nst,
    float* __restrict__ nsr) {
  __shared__ union SM {
    struct G {
      alignas(16) unsigned short As[16 * 512];  // reused as hp fp32[16][256]
      float sred[16][4];
    } g;
    struct N {
      alignas(16) float rh_s[R_ * HE_];  // 49 KB
      alignas(16) float wh_s[8 * HE_];   // 8 KB
      int plist[400];
      float nst_l[8];
      float nsr_l[52];
      int cnt_s[8];
      int off_s[8];
      int P;
    } n;
  } sm;
  int tid = threadIdx.x, wave = tid >> 6, lane = tid & 63;
  int bid = blockIdx.x;

  if (bid < NG_GEMM2) {
    int row0 = bid * 16;
    const float4* A4 = (const float4*)(pos + (size_t)row0 * D_);
#pragma unroll
    for (int it = 0; it < 4; ++it) {
      int f = it * 512 + tid;
      int row = f >> 7, kq = f & 127;
      float4 v = A4[f];
      int bo = (row * 1024 + kq * 8) ^ ((row & 7) << 4);
      s16x4 pk;
      pk[0] = (short)bf16rne(v.x);
      pk[1] = (short)bf16rne(v.y);
      pk[2] = (short)bf16rne(v.z);
      pk[3] = (short)bf16rne(v.w);
      *(s16x4*)((char*)sm.g.As + bo) = pk;
    }
    __syncthreads();
    int rl = lane & 15, kg = lane >> 4;
    f32x4 acc0 = {0.f, 0.f, 0.f, 0.f}, acc1 = {0.f, 0.f, 0.f, 0.f};
    const s16x8* Wp8 = (const s16x8*)wpack + 16384;  // mat 1 = pw1
    int ct0 = wave, ct1 = wave + 8;
#pragma unroll
    for (int kt = 0; kt < 16; ++kt) {
      int bo = (rl * 1024 + kt * 64 + kg * 16) ^ ((rl & 7) << 4);
      s16x8 af = *(const s16x8*)((char*)sm.g.As + bo);
      s16x8 b0 = Wp8[(size_t)(kt * 16 + ct0) * 64 + lane];
      s16x8 b1 = Wp8[(size_t)(kt * 16 + ct1) * 64 + lane];
      acc0 = __builtin_amdgcn_mfma_f32_16x16x32_bf16(af, b0, acc0, 0, 0, 0);
      acc1 = __builtin_amdgcn_mfma_f32_16x16x32_bf16(af, b1, acc1, 0, 0, 0);
    }
    __syncthreads();  // all A-tile reads done; reuse LDS for hp
    float* hp_s = (float*)sm.g.As;  // [16][256] fp32 = 16 KB
#pragma unroll
    for (int q = 0; q < 4; ++q) {
      hp_s[(kg * 4 + q) * 256 + ct0 * 16 + rl] = acc0[q];
      hp_s[(kg * 4 + q) * 256 + ct1 * 16 + rl] = acc1[q];
    }
    __syncthreads();
    int c = tid & 255, jh = tid >> 8;
    float pb1c = pb1[c], pw2c = pw2[c];
#pragma unroll
    for (int jj = 0; jj < 8; ++jj) {
      int j = jh * 8 + jj;
      float v = tanh_fast(hp_s[j * 256 + c] + pb1c) * pw2c;
      v = wave_sum(v);
      if (lane == 0) sm.g.sred[j][wave & 3] = v;
    }
    __syncthreads();
    if (tid < 16) {
      float s = sm.g.sred[tid][0] + sm.g.sred[tid][1] + sm.g.sred[tid][2] +
                sm.g.sred[tid][3] + pb2[0];
      s = sigmoid_fast(s);
      int row = row0 + tid;
      if (negcnt[row] == 0.f) s = 0.f;
      s *= (float)amask[row];
      pscore[row] = fmaxf(s, 0.f);
    }
    return;
  }

  // ---- neg-expert, LDS-tiled
  int nb = bid - NG_GEMM2;
  int b = nb >> 4, t0 = (nb & 15) * 8;
  int bt0 = b * T_ + t0;
  {
    const float4* src = (const float4*)(rh + (size_t)b * R_ * HE_);
    float4* dst = (float4*)sm.n.rh_s;
    for (int i = tid; i < R_ * (HE_ / 4); i += 512) dst[i] = src[i];
    const float4* srcw = (const float4*)(wh + (size_t)bt0 * HE_);
    float4* dstw = (float4*)sm.n.wh_s;
    for (int i = tid; i < 8 * (HE_ / 4); i += 512) dstw[i] = srcw[i];
  }
  if (tid < 8) {
    sm.n.nst_l[tid] = 0.f;
    sm.n.cnt_s[tid] = __popcll(nmask[bt0 + tid]);
  }
  if (tid < R_) sm.n.nsr_l[tid] = 0.f;
  __syncthreads();
  if (tid == 0) {
    int tot = 0;
#pragma unroll
    for (int w = 0; w < 8; ++w) {
      sm.n.off_s[w] = tot;
      tot += sm.n.cnt_s[w];
    }
    sm.n.P = tot;
  }
  __syncthreads();
  {
    unsigned long long mw = nmask[bt0 + wave];
    if (lane < R_ && ((mw >> lane) & 1ull)) {
      int pfx = __popcll(mw & ((1ull << lane) - 1ull));
      sm.n.plist[sm.n.off_s[wave] + pfx] = (wave << 6) | lane;
    }
  }
  __syncthreads();
  int P = sm.n.P;
  int grp = tid >> 4, gl = tid & 15;
  // per-lane fixed weight chunks matching the rotated read order
  float4 wnr[4];
#pragma unroll
  for (int k = 0; k < 4; ++k)
    wnr[k] = ((const float4*)nw2)[4 * gl + ((gl + k) & 3)];
  float bias = nb2[0];
  for (int i = grp; i < P; i += 32) {
    int tr = sm.n.plist[i];
    int t = tr >> 6, r = tr & 63;
    const float4* wrow = (const float4*)(sm.n.wh_s + t * HE_);
    const float4* rrow = (const float4*)(sm.n.rh_s + r * HE_);
    float acc = 0.f;
#pragma unroll
    for (int k = 0; k < 4; ++k) {
      int c = 4 * gl + ((gl + k) & 3);  // rotation: 16 lanes hit all 32 banks
      float4 hw = wrow[c];
      float4 hr = rrow[c];
      float4 wn = wnr[k];
      acc = fmaf(tanh_fast(hw.x + hr.x), wn.x, acc);
      acc = fmaf(tanh_fast(hw.y + hr.y), wn.y, acc);
      acc = fmaf(tanh_fast(hw.z + hr.z), wn.z, acc);
      acc = fmaf(tanh_fast(hw.w + hr.w), wn.w, acc);
    }
    acc += __shfl_xor(acc, 1);
    acc += __shfl_xor(acc, 2);
    acc += __shfl_xor(acc, 4);
    acc += __shfl_xor(acc, 8);
    if (gl == 0) {
      float s = sigmoid_fast(acc + bias);  // relu(sigmoid) == sigmoid
      atomicAdd(&sm.n.nst_l[t], s);
      atomicAdd(&sm.n.nsr_l[r], s);
    }
  }
  __syncthreads();
  if (tid < 8) {
    nst[bt0 + tid] = sm.n.nst_l[tid];  // token owned by exactly this block
  } else if (tid >= 64 && tid < 64 + R_) {
    atomicAdd(&nsr[b * R_ + (tid - 64)], sm.n.nsr_l[tid - 64]);
  }
}

// ---------------------------------------------------------------------------
// K7a: parallel aggregates from the precomputed marginals.
// Block = (b, 64-d chunk), 512 threads.
// ---------------------------------------------------------------------------
__global__ __launch_bounds__(512) void k7a_agg(
    const float* __restrict__ word, const float* __restrict__ region,
    const float* __restrict__ pos, const float* __restrict__ pscore,
    const float* __restrict__ nst, const float* __restrict__ nsr,
    float* __restrict__ nagg, float* __restrict__ pagg) {
  int b = blockIdx.x >> 3, dc = blockIdx.x & 7;
  int tid = threadIdx.x;
  int dl = tid & 63, ts = tid >> 6;
  int d = dc * 64 + dl;
  __shared__ float nst_s[T_], psc_s[T_], nsr_s[R_];
  __shared__ float redn[8][64], redp[8][64];
  if (tid < T_) {
    psc_s[tid] = pscore[b * T_ + tid];
    nst_s[tid] = nst[b * T_ + tid];
  } else if (tid < T_ + R_) {
    nsr_s[tid - T_] = nsr[b * R_ + (tid - T_)];
  }
  __syncthreads();
  float na = 0.f, pa = 0.f;
  for (int t = ts; t < T_; t += 8) {
    size_t base = ((size_t)(b * T_ + t)) * D_ + d;
    na = fmaf(nst_s[t], word[base], na);
    pa = fmaf(psc_s[t], pos[base], pa);
  }
  for (int r = ts; r < R_; r += 8)
    na = fmaf(nsr_s[r], region[((size_t)(b * R_ + r)) * D_ + d], na);
  redn[ts][dl] = na;
  redp[ts][dl] = pa;
  __syncthreads();
  if (tid < 64) {
    float s = 0.f;
#pragma unroll
    for (int k = 0; k < 8; ++k) s += redn[k][tid];
    nagg[(size_t)b * D_ + dc * 64 + tid] = s;
  } else if (tid < 128) {
    int l = tid - 64;
    float s = 0.f;
#pragma unroll
    for (int k = 0; k < 8; ++k) s += redp[k][l];
    pagg[(size_t)b * D_ + dc * 64 + l] = s;
  }
}

// ---------------------------------------------------------------------------
// K7b: per-batch tail: choose, path_prob, final, classifier.
// ---------------------------------------------------------------------------
__global__ __launch_bounds__(256) void k7b_tail(
    const float* __restrict__ nagg, const float* __restrict__ pagg,
    const float* __restrict__ negcnt, const float* __restrict__ fcw,
    const float* __restrict__ fcb, const float* __restrict__ cw1,
    const float* __restrict__ cb1, const float* __restrict__ cw2,
    const float* __restrict__ cb2, float* __restrict__ out) {
  int b = blockIdx.x, tid = threadIdx.x, lane = tid & 63, wave = tid >> 6;
  __shared__ float na_s[D_], pa_s[D_], fin[D_];
  __shared__ float red[8];
  __shared__ float pp0, pp1;
  float cntp = (tid < T_) ? negcnt[b * T_ + tid] : 0.f;
  float cw = wave_sum(cntp);
  if (lane == 0) red[wave] = cw;
  int d0 = tid, d1 = tid + 256;
  float n0 = nagg[(size_t)b * D_ + d0], n1 = nagg[(size_t)b * D_ + d1];
  float p0 = pagg[(size_t)b * D_ + d0], p1 = pagg[(size_t)b * D_ + d1];
  na_s[d0] = n0;
  na_s[d1] = n1;
  pa_s[d0] = p0;
  pa_s[d1] = p1;
  __syncthreads();
  float cnt_total = red[0] + red[1] + red[2] + red[3];
  float f0 = fcw[d0], f1 = fcw[d1];
  float c0p = n0 * f0 + n1 * f1;
  float c1p = p0 * f0 + p1 * f1;
  c0p = wave_sum(c0p);
  c1p = wave_sum(c1p);
  __syncthreads();
  if (lane == 0) { red[wave] = c0p; red[wave + 4] = c1p; }
  __syncthreads();
  if (tid == 0) {
    float c0 = red[0] + red[1] + red[2] + red[3] + fcb[0];
    float c1 = red[4] + red[5] + red[6] + red[7] + fcb[0];
    if (cnt_total == 0.f) c0 = -1e9f;
    float m = fmaxf(c0, c1);
    float e0 = __expf(c0 - m), e1 = __expf(c1 - m);
    float inv = 1.f / (e0 + e1);
    pp0 = e0 * inv;
    pp1 = e1 * inv;
    out[2 * B_ + 2 * b + 0] = pp0;
    out[2 * B_ + 2 * b + 1] = pp1;
  }
  __syncthreads();
  for (int d = tid; d < D_; d += 256) fin[d] = pp0 * na_s[d] + pp1 * pa_s[d];
  __syncthreads();
  // 4-way split accumulator: breaks the 512-deep serial fma chain
  float a0 = cb1[tid], a1 = 0.f, a2 = 0.f, a3 = 0.f;
#pragma unroll 4
  for (int d = 0; d < D_; d += 4) {
    a0 = fmaf(fin[d + 0], cw1[(size_t)(d + 0) * HC_ + tid], a0);
    a1 = fmaf(fin[d + 1], cw1[(size_t)(d + 1) * HC_ + tid], a1);
    a2 = fmaf(fin[d + 2], cw1[(size_t)(d + 2) * HC_ + tid], a2);
    a3 = fmaf(fin[d + 3], cw1[(size_t)(d + 3) * HC_ + tid], a3);
  }
  float acc = fmaxf((a0 + a1) + (a2 + a3), 0.f);
  float l0 = acc * cw2[2 * tid + 0];
  float l1 = acc * cw2[2 * tid + 1];
  l0 = wave_sum(l0);
  l1 = wave_sum(l1);
  __syncthreads();
  if (lane == 0) { red[wave] = l0; red[wave + 4] = l1; }
  __syncthreads();
  if (tid == 0) {
    out[2 * b + 0] = red[0] + red[1] + red[2] + red[3] + cb2[0];
    out[2 * b + 1] = red[4] + red[5] + red[6] + red[7] + cb2[1];
  }
}

extern "C" void kernel_launch(void* const* d_in, const int* in_sizes, int n_in,
                              void* d_out, int out_size, void* d_ws,
                              size_t ws_size, hipStream_t stream) {
  const float* word = (const float*)d_in[0];
  const float* region = (const float*)d_in[1];
  const int* amask = (const int*)d_in[2];
  const float* pw1 = (const float*)d_in[3];
  const float* pb1 = (const float*)d_in[4];
  const float* pw2 = (const float*)d_in[5];
  const float* pb2 = (const float*)d_in[6];
  const float* nw1 = (const float*)d_in[7];
  const float* nb1 = (const float*)d_in[8];
  const float* nw2 = (const float*)d_in[9];
  const float* nb2 = (const float*)d_in[10];
  const float* fcw = (const float*)d_in[11];
  const float* fcb = (const float*)d_in[12];
  const float* cw1 = (const float*)d_in[13];
  const float* cb1 = (const float*)d_in[14];
  const float* cw2 = (const float*)d_in[15];
  const float* cb2 = (const float*)d_in[16];
  float* out = (float*)d_out;

  unsigned short* wpack = (unsigned short*)d_ws;  // 2*131072 bf16 = 512 KB
  float* ws = (float*)d_ws + 131072;
  float* pos = ws;                              // B*T*D
  float* wh = pos + (size_t)B_ * T_ * D_;       // B*T*HE
  float* rh = wh + (size_t)B_ * T_ * HE_;       // B*R*HE
  float* nst = rh + (size_t)B_ * R_ * HE_;      // B*T  (neg-score sum over r)
  float* nsr = nst + (size_t)B_ * T_;           // B*R  (neg-score sum over t)
  float* negcnt = nsr + (size_t)B_ * R_;        // B*T
  float* pscore = negcnt + B_ * T_;             // B*T
  float* nagg = pscore + B_ * T_;               // B*D
  float* pagg = nagg + (size_t)B_ * D_;         // B*D
  unsigned long long* nmask =
      (unsigned long long*)(pagg + (size_t)B_ * D_);  // B*T (8B each)

  pack_w<<<128, 256, 0, stream>>>(nw1, pw1, wpack, nsr);
  m1_gemm_k1<<<NG_GEMM1 + NG_K1, 512, 0, stream>>>(
      word, region, wpack, nb1, amask, wh, rh, pos, negcnt, nmask);
  m2_hps_neg<<<NG_GEMM2 + NG_NEGB, 512, 0, stream>>>(
      pos, wpack, pb1, pw2, pb2, negcnt, amask, wh, rh, nw2, nb2, nmask,
      pscore, nst, nsr);
  k7a_agg<<<B_ * 8, 512, 0, stream>>>(word, region, pos, pscore, nst, nsr,
                                      nagg, pagg);
  k7b_tail<<<B_, 256, 0, stream>>>(nagg, pagg, negcnt, fcw, fcb, cw1, cb1,
                                   cw2, cb2, out);
}